// Round 10
// baseline (587.338 us; speedup 1.0000x reference)
//
#include <hip/hip_runtime.h>
#include <hip/hip_fp16.h>

#define E_EDGES 320000
#define NF 20

typedef float v4 __attribute__((ext_vector_type(4)));
typedef float v2f __attribute__((ext_vector_type(2)));

#if defined(__has_builtin)
# if __has_builtin(__builtin_elementwise_fma)
#  define EWFMA(a,b,c) __builtin_elementwise_fma((a),(b),(c))
# endif
#endif
#ifndef EWFMA
# define EWFMA(a,b,c) ((a)*(b)+(c))
#endif
#if defined(__has_builtin)
# if __has_builtin(__builtin_elementwise_max)
#  define EWMAX(a,b) __builtin_elementwise_max((a),(b))
#  define EWMIN(a,b) __builtin_elementwise_min((a),(b))
# endif
#endif

__device__ __forceinline__ v4 bc4(float s) { return (v4){s, s, s, s}; }
__device__ __forceinline__ v4 v4z() { return (v4){0.f, 0.f, 0.f, 0.f}; }

__device__ __forceinline__ float selu_f(float x) {
    const float scale = 1.0507009873554805f;
    const float alpha = 1.6732632423543772f;
    float p = fmaxf(x, 0.f);
    float m = fminf(x, 0.f);
    float e = __expf(m);
    return fmaf(scale, p, scale * alpha * (e - 1.f));
}
__device__ __forceinline__ float sigmoid_f(float x) {
    return 1.f / (1.f + __expf(-x));
}
__device__ __forceinline__ v4 selu4(v4 x) {
    const float scale = 1.0507009873554805f;
    const float ka = 1.0507009873554805f * 1.6732632423543772f;
#ifdef EWMAX
    v4 p = EWMAX(x, v4z());
    v4 m = EWMIN(x, v4z());
#else
    v4 p = {fmaxf(x.x,0.f), fmaxf(x.y,0.f), fmaxf(x.z,0.f), fmaxf(x.w,0.f)};
    v4 m = {fminf(x.x,0.f), fminf(x.y,0.f), fminf(x.z,0.f), fminf(x.w,0.f)};
#endif
    v4 e = {__expf(m.x), __expf(m.y), __expf(m.z), __expf(m.w)};
    return EWFMA(bc4(scale), p, EWFMA(bc4(ka), e, bc4(-ka)));
}

__device__ __forceinline__ float hsum4(v4 x) {
    v2f lo = __builtin_shufflevector(x, x, 0, 1);
    v2f hi = __builtin_shufflevector(x, x, 2, 3);
    v2f h = lo + hi;
    return h.x + h.y;
}

__device__ __forceinline__ float dot20v(v4 a0, v4 a1, v4 a2, v4 a3, v4 a4,
                                        const v4* __restrict__ w) {
    v4 w0 = w[0], w1 = w[1], w2 = w[2], w3 = w[3], w4 = w[4];
    v4 x = a0 * w0;
    x = EWFMA(a1, w1, x); x = EWFMA(a2, w2, x);
    x = EWFMA(a3, w3, x); x = EWFMA(a4, w4, x);
    return hsum4(x);
}
__device__ __forceinline__ void dot20_dualv(const v4* __restrict__ w,
    v4 a0, v4 a1, v4 a2, v4 a3, v4 a4,
    v4 b0, v4 b1, v4 b2, v4 b3, v4 b4,
    float& r0, float& r1)
{
    v4 w0 = w[0], w1 = w[1], w2 = w[2], w3 = w[3], w4 = w[4];
    v4 xa = a0 * w0;
    xa = EWFMA(a1, w1, xa); xa = EWFMA(a2, w2, xa);
    xa = EWFMA(a3, w3, xa); xa = EWFMA(a4, w4, xa);
    v4 xb = b0 * w0;
    xb = EWFMA(b1, w1, xb); xb = EWFMA(b2, w2, xb);
    xb = EWFMA(b3, w3, xb); xb = EWFMA(b4, w4, xb);
    r0 = hsum4(xa);
    r1 = hsum4(xb);
}
__device__ __forceinline__ void h8_to_v4x2(uint4 r, v4& lo, v4& hi) {
    float2 fa = __half22float2(__builtin_bit_cast(__half2, r.x));
    float2 fb = __half22float2(__builtin_bit_cast(__half2, r.y));
    float2 fc = __half22float2(__builtin_bit_cast(__half2, r.z));
    float2 fd = __half22float2(__builtin_bit_cast(__half2, r.w));
    lo = (v4){fa.x, fa.y, fb.x, fb.y};
    hi = (v4){fc.x, fc.y, fd.x, fd.y};
}
__device__ __forceinline__ uint4 f8_to_h8(v4 lo, v4 hi) {
    uint4 r;
    r.x = __builtin_bit_cast(unsigned, __floats2half2_rn(lo.x, lo.y));
    r.y = __builtin_bit_cast(unsigned, __floats2half2_rn(lo.z, lo.w));
    r.z = __builtin_bit_cast(unsigned, __floats2half2_rn(hi.x, hi.y));
    r.w = __builtin_bit_cast(unsigned, __floats2half2_rn(hi.z, hi.w));
    return r;
}

#define FOR20(X) \
  X(0, v0.x) X(1, v0.y) X(2, v0.z) X(3, v0.w) \
  X(4, v1.x) X(5, v1.y) X(6, v1.z) X(7, v1.w) \
  X(8, v2.x) X(9, v2.y) X(10, v2.z) X(11, v2.w) \
  X(12, v3.x) X(13, v3.y) X(14, v3.z) X(15, v3.w) \
  X(16, v4v.x) X(17, v4v.y) X(18, v4v.z) X(19, v4v.w)

#define FOR20_2(X) \
  X(0, va0.x, vb0.x) X(1, va0.y, vb0.y) X(2, va0.z, vb0.z) X(3, va0.w, vb0.w) \
  X(4, va1.x, vb1.x) X(5, va1.y, vb1.y) X(6, va1.z, vb1.z) X(7, va1.w, vb1.w) \
  X(8, va2.x, vb2.x) X(9, va2.y, vb2.y) X(10, va2.z, vb2.z) X(11, va2.w, vb2.w) \
  X(12, va3.x, vb3.x) X(13, va3.y, vb3.y) X(14, va3.z, vb3.z) X(15, va3.w, vb3.w) \
  X(16, va4.x, vb4.x) X(17, va4.y, vb4.y) X(18, va4.z, vb4.z) X(19, va4.w, vb4.w)

#define FOR8S2(X) \
  X(0, sa0.x, sb0.x) X(1, sa0.y, sb0.y) X(2, sa0.z, sb0.z) X(3, sa0.w, sb0.w) \
  X(4, sa1.x, sb1.x) X(5, sa1.y, sb1.y) X(6, sa1.z, sb1.z) X(7, sa1.w, sb1.w)

// Initial B table from edge_attr (runs ONCE)
__global__ void __launch_bounds__(256) kernel_B0(
    const float* __restrict__ h, const float* __restrict__ W1,
    const float* __restrict__ b1, __half* __restrict__ B)
{
    __shared__ __align__(16) float sw[640];
    __shared__ __align__(16) float sbias[32];
    for (int i = threadIdx.x; i < 640; i += 256) sw[i] = W1[640 + i];
    if (threadIdx.x < 32) sbias[threadIdx.x] = b1[threadIdx.x];
    __syncthreads();
    int e = blockIdx.x * 256 + threadIdx.x;
    const v4* hp = reinterpret_cast<const v4*>(h + (size_t)e * NF);
    v4 v0 = hp[0], v1 = hp[1], v2 = hp[2], v3 = hp[3], v4v = hp[4];
    const v4* bi = reinterpret_cast<const v4*>(sbias);
    v4 c0 = bi[0], c1 = bi[1], c2 = bi[2], c3 = bi[3],
       c4 = bi[4], c5 = bi[5], c6 = bi[6], c7 = bi[7];
    #define BSTEP(f, hf) { v4 t_ = bc4(hf); const v4* w_ = (const v4*)&sw[(f)*32]; \
        c0 = EWFMA(t_, w_[0], c0); c1 = EWFMA(t_, w_[1], c1); \
        c2 = EWFMA(t_, w_[2], c2); c3 = EWFMA(t_, w_[3], c3); \
        c4 = EWFMA(t_, w_[4], c4); c5 = EWFMA(t_, w_[5], c5); \
        c6 = EWFMA(t_, w_[6], c6); c7 = EWFMA(t_, w_[7], c7); }
    FOR20(BSTEP)
    #undef BSTEP
    uint4* Bp = reinterpret_cast<uint4*>(B + (size_t)e * 32);
    Bp[0] = f8_to_h8(c0, c1); Bp[1] = f8_to_h8(c2, c3);
    Bp[2] = f8_to_h8(c4, c5); Bp[3] = f8_to_h8(c6, c7);
}

// One step. 4 lanes/quad, 2 edges/thread, fp16 B gather, rolled GRU, pk-fp32.
// WRITE_B: fused epilogue computes next step's B from h_out via an L1-hot
// global re-read after __syncthreads() (vmcnt drained -> same-CU visibility).
// No shfl h-reconstruction (R6's VGPR blowup) and no extra LDS region.
template<int WRITE_B>
__global__ void __launch_bounds__(256) kernel_step(
    const float* __restrict__ h_in, float* __restrict__ h_out,
    const __half* __restrict__ Br, __half* __restrict__ Bw,
    const int* __restrict__ dst,
    const float* __restrict__ W1, const float* __restrict__ b1,
    const float* __restrict__ W2, const float* __restrict__ b2,
    const float* __restrict__ Wih, const float* __restrict__ Whh,
    const float* __restrict__ bih, const float* __restrict__ bhh)
{
    __shared__ __align__(16) float sW1[640];   // rows 0-19 of msg_W1 (20,32)
    __shared__ __align__(16) float sW1b[640];  // rows 20-39 (epilogue B-write)
    __shared__ __align__(16) float sW2[640];   // (32,20)
    __shared__ __align__(16) float sb2v[20];
    __shared__ __align__(16) float sb1v[32];
    __shared__ __align__(16) float sWih[1200]; // (60,20)
    __shared__ __align__(16) float sWhh[1200];
    __shared__ float sbih[60];
    __shared__ float sbhh[60];
    for (int i = threadIdx.x; i < 640; i += 256) { sW1[i] = W1[i]; sW2[i] = W2[i]; }
    if (WRITE_B) {
        for (int i = threadIdx.x; i < 640; i += 256) sW1b[i] = W1[640 + i];
        if (threadIdx.x >= 192 && threadIdx.x < 224) sb1v[threadIdx.x - 192] = b1[threadIdx.x - 192];
    }
    for (int i = threadIdx.x; i < 1200; i += 256) { sWih[i] = Wih[i]; sWhh[i] = Whh[i]; }
    if (threadIdx.x < 20) sb2v[threadIdx.x] = b2[threadIdx.x];
    else if (threadIdx.x >= 64 && threadIdx.x < 124) sbih[threadIdx.x - 64] = bih[threadIdx.x - 64];
    else if (threadIdx.x >= 128 && threadIdx.x < 188) sbhh[threadIdx.x - 128] = bhh[threadIdx.x - 128];
    __syncthreads();

    int t = blockIdx.x * 256 + threadIdx.x;
    int p = t >> 2;
    int q = t & 3;
    int ob = q * 8;
    int e0 = p * 2, e1 = p * 2 + 1;

    int2 dd = *reinterpret_cast<const int2*>(dst + e0);
    int d0 = dd.x, d1 = dd.y;

    const v4* hp0 = reinterpret_cast<const v4*>(h_in + (size_t)e0 * NF);
    const v4* hp1 = reinterpret_cast<const v4*>(h_in + (size_t)e1 * NF);
    v4 va0 = hp0[0], va1 = hp0[1], va2 = hp0[2], va3 = hp0[3], va4 = hp0[4];
    v4 vb0 = hp1[0], vb1 = hp1[1], vb2 = hp1[2], vb3 = hp1[3], vb4 = hp1[4];

    // A slices for both edges (shared LDS weight reads, pk-fma)
    v4 aa0 = v4z(), aa1 = v4z(), ab0 = v4z(), ab1 = v4z();
    #define ASTEP2(f, h0, h1) { const v4* w_ = (const v4*)&sW1[(f)*32 + ob]; \
        v4 w0_ = w_[0], w1_ = w_[1]; \
        v4 t0_ = bc4(h0), t1_ = bc4(h1); \
        aa0 = EWFMA(t0_, w0_, aa0); aa1 = EWFMA(t0_, w1_, aa1); \
        ab0 = EWFMA(t1_, w0_, ab0); ab1 = EWFMA(t1_, w1_, ab1); }
    FOR20_2(ASTEP2)
    #undef ASTEP2

    // gather 16 fp16 rows per edge; 1 dwordx4 per row per edge = lane's 8 chans
    const uint4* Bp0 = reinterpret_cast<const uint4*>(Br) + (size_t)d0 * 64 + q;
    const uint4* Bp1 = reinterpret_cast<const uint4*>(Br) + (size_t)d1 * 64 + q;
    v4 sa0 = v4z(), sa1 = v4z(), sb0 = v4z(), sb1 = v4z();
    #pragma unroll 4
    for (int k = 0; k < 16; k++) {
        uint4 rA = Bp0[k * 4];
        uint4 rB = Bp1[k * 4];
        v4 loA, hiA, loB, hiB;
        h8_to_v4x2(rA, loA, hiA);
        h8_to_v4x2(rB, loB, hiB);
        sa0 = sa0 + selu4(aa0 + loA);
        sa1 = sa1 + selu4(aa1 + hiA);
        sb0 = sb0 + selu4(ab0 + loB);
        sb1 = sb1 + selu4(ab1 + hiB);
    }

    // partial agg (shared W2 rows, pk-fma)
    v4 ga0 = v4z(), ga1 = v4z(), ga2 = v4z(), ga3 = v4z(), ga4 = v4z();
    v4 gb0 = v4z(), gb1 = v4z(), gb2 = v4z(), gb3 = v4z(), gb4 = v4z();
    #define AGGS2(j, c0_, c1_) { const v4* w_ = (const v4*)&sW2[(ob + (j)) * 20]; \
        v4 w0_ = w_[0], w1_ = w_[1], w2_ = w_[2], w3_ = w_[3], w4_ = w_[4]; \
        v4 u_ = bc4(c0_), vv_ = bc4(c1_); \
        ga0 = EWFMA(u_, w0_, ga0); ga1 = EWFMA(u_, w1_, ga1); ga2 = EWFMA(u_, w2_, ga2); \
        ga3 = EWFMA(u_, w3_, ga3); ga4 = EWFMA(u_, w4_, ga4); \
        gb0 = EWFMA(vv_, w0_, gb0); gb1 = EWFMA(vv_, w1_, gb1); gb2 = EWFMA(vv_, w2_, gb2); \
        gb3 = EWFMA(vv_, w3_, gb3); gb4 = EWFMA(vv_, w4_, gb4); }
    FOR8S2(AGGS2)
    #undef AGGS2

    // quad butterfly
    #define BF1(r_, m_) { v4 t_ = { __shfl_xor(r_.x, m_), __shfl_xor(r_.y, m_), \
                                    __shfl_xor(r_.z, m_), __shfl_xor(r_.w, m_) }; \
                          r_ = r_ + t_; }
    #define BFLY(m_) BF1(ga0, m_) BF1(ga1, m_) BF1(ga2, m_) BF1(ga3, m_) BF1(ga4, m_) \
                     BF1(gb0, m_) BF1(gb1, m_) BF1(gb2, m_) BF1(gb3, m_) BF1(gb4, m_)
    BFLY(1)
    BFLY(2)
    #undef BFLY
    #undef BF1

    {
        const v4* b2p = reinterpret_cast<const v4*>(sb2v);
        v4 sixteen = bc4(16.f);
        v4 c0 = b2p[0], c1 = b2p[1], c2 = b2p[2], c3 = b2p[3], c4 = b2p[4];
        ga0 = EWFMA(sixteen, c0, ga0); ga1 = EWFMA(sixteen, c1, ga1); ga2 = EWFMA(sixteen, c2, ga2);
        ga3 = EWFMA(sixteen, c3, ga3); ga4 = EWFMA(sixteen, c4, ga4);
        gb0 = EWFMA(sixteen, c0, gb0); gb1 = EWFMA(sixteen, c1, gb1); gb2 = EWFMA(sixteen, c2, gb2);
        gb3 = EWFMA(sixteen, c3, gb3); gb4 = EWFMA(sixteen, c4, gb4);
    }

    // GRU: 5 channels per lane, ROLLED (dynamic index -> LDS only; VGPR=64)
    for (int i = 0; i < 5; i++) {
        int c = q * 5 + i;
        float ir0, ir1, iz0, iz1, in0, in1, hr0, hr1, hz0, hz1, hn0, hn1;
        dot20_dualv((const v4*)&sWih[c * 20],        ga0, ga1, ga2, ga3, ga4,
                    gb0, gb1, gb2, gb3, gb4, ir0, ir1);
        dot20_dualv((const v4*)&sWih[(20 + c) * 20], ga0, ga1, ga2, ga3, ga4,
                    gb0, gb1, gb2, gb3, gb4, iz0, iz1);
        dot20_dualv((const v4*)&sWih[(40 + c) * 20], ga0, ga1, ga2, ga3, ga4,
                    gb0, gb1, gb2, gb3, gb4, in0, in1);
        dot20_dualv((const v4*)&sWhh[c * 20],        va0, va1, va2, va3, va4,
                    vb0, vb1, vb2, vb3, vb4, hr0, hr1);
        dot20_dualv((const v4*)&sWhh[(20 + c) * 20], va0, va1, va2, va3, va4,
                    vb0, vb1, vb2, vb3, vb4, hz0, hz1);
        dot20_dualv((const v4*)&sWhh[(40 + c) * 20], va0, va1, va2, va3, va4,
                    vb0, vb1, vb2, vb3, vb4, hn0, hn1);
        float bi_r = sbih[c], bi_z = sbih[20 + c], bi_n = sbih[40 + c];
        float bh_r = sbhh[c], bh_z = sbhh[20 + c], bh_n = sbhh[40 + c];
        {
            float r = sigmoid_f(bi_r + ir0 + bh_r + hr0);
            float z = sigmoid_f(bi_z + iz0 + bh_z + hz0);
            float xn = bi_n + in0 + r * (bh_n + hn0);
            xn = fminf(fmaxf(xn, -20.f), 20.f);
            float tt = __expf(2.f * xn);
            float n = (tt - 1.f) / (tt + 1.f);
            float hc = h_in[(size_t)e0 * NF + c];
            h_out[(size_t)e0 * NF + c] = (1.f - z) * n + z * hc;
        }
        {
            float r = sigmoid_f(bi_r + ir1 + bh_r + hr1);
            float z = sigmoid_f(bi_z + iz1 + bh_z + hz1);
            float xn = bi_n + in1 + r * (bh_n + hn1);
            xn = fminf(fmaxf(xn, -20.f), 20.f);
            float tt = __expf(2.f * xn);
            float n = (tt - 1.f) / (tt + 1.f);
            float hc = h_in[(size_t)e1 * NF + c];
            h_out[(size_t)e1 * NF + c] = (1.f - z) * n + z * hc;
        }
    }

    if (WRITE_B) {
        // barrier drains vmcnt -> all block-local h_out writes L1-visible
        __syncthreads();
        const v4* b1p = (const v4*)&sb1v[ob];
        v4 bbA0 = b1p[0], bbA1 = b1p[1];
        v4 bbB0 = bbA0, bbB1 = bbA1;
        const float* ho0 = h_out + (size_t)e0 * NF;
        const float* ho1 = h_out + (size_t)e1 * NF;
        #pragma unroll
        for (int f = 0; f < 20; f++) {
            float hf0 = ho0[f];
            float hf1 = ho1[f];
            const v4* w_ = (const v4*)&sW1b[f * 32 + ob];
            v4 w0 = w_[0], w1 = w_[1];
            v4 t0 = bc4(hf0), t1 = bc4(hf1);
            bbA0 = EWFMA(t0, w0, bbA0); bbA1 = EWFMA(t0, w1, bbA1);
            bbB0 = EWFMA(t1, w0, bbB0); bbB1 = EWFMA(t1, w1, bbB1);
        }
        uint4* bw = reinterpret_cast<uint4*>(Bw);
        bw[(size_t)e0 * 4 + q] = f8_to_h8(bbA0, bbA1);
        bw[(size_t)e1 * 4 + q] = f8_to_h8(bbB0, bbB1);
    }
}

__global__ void __launch_bounds__(256) kernel_readout(
    const float* __restrict__ h,
    const float* __restrict__ W1, const float* __restrict__ b1,
    const float* __restrict__ W2, const float* __restrict__ b2,
    const float* __restrict__ W3, const float* __restrict__ b3,
    float* __restrict__ out)
{
    __shared__ __align__(16) float sW1t[1280]; // transposed: (64,20)
    __shared__ float sb1[64];
    __shared__ __align__(16) float sW2[2048];  // (64,32)
    __shared__ __align__(16) float sb2v[32];
    __shared__ __align__(16) float sW3[32];
    __shared__ float sb3;
    for (int i = threadIdx.x; i < 1280; i += 256) {
        int f = i >> 6, o = i & 63;
        sW1t[o * 20 + f] = W1[i];
    }
    for (int i = threadIdx.x; i < 2048; i += 256) sW2[i] = W2[i];
    if (threadIdx.x < 64) sb1[threadIdx.x] = b1[threadIdx.x];
    else if (threadIdx.x >= 64 && threadIdx.x < 96) sb2v[threadIdx.x - 64] = b2[threadIdx.x - 64];
    else if (threadIdx.x >= 96 && threadIdx.x < 128) sW3[threadIdx.x - 96] = W3[threadIdx.x - 96];
    if (threadIdx.x == 128) sb3 = b3[0];
    __syncthreads();

    int e = blockIdx.x * 256 + threadIdx.x;
    const v4* hp = reinterpret_cast<const v4*>(h + (size_t)e * NF);
    v4 v0 = hp[0], v1 = hp[1], v2 = hp[2], v3 = hp[3], v4v = hp[4];

    const v4* b2p = reinterpret_cast<const v4*>(sb2v);
    v4 x20 = b2p[0], x21 = b2p[1], x22 = b2p[2], x23 = b2p[3],
       x24 = b2p[4], x25 = b2p[5], x26 = b2p[6], x27 = b2p[7];
    for (int o = 0; o < 64; o++) {
        float x1 = sb1[o] + dot20v(v0, v1, v2, v3, v4v, (const v4*)&sW1t[o * 20]);
        x1 = selu_f(x1);
        v4 xb = bc4(x1);
        const v4* w = (const v4*)&sW2[o * 32];
        x20 = EWFMA(xb, w[0], x20); x21 = EWFMA(xb, w[1], x21);
        x22 = EWFMA(xb, w[2], x22); x23 = EWFMA(xb, w[3], x23);
        x24 = EWFMA(xb, w[4], x24); x25 = EWFMA(xb, w[5], x25);
        x26 = EWFMA(xb, w[6], x26); x27 = EWFMA(xb, w[7], x27);
    }
    const v4* w3p = reinterpret_cast<const v4*>(sW3);
    v4 accv = selu4(x20) * w3p[0];
    accv = EWFMA(selu4(x21), w3p[1], accv);
    accv = EWFMA(selu4(x22), w3p[2], accv);
    accv = EWFMA(selu4(x23), w3p[3], accv);
    accv = EWFMA(selu4(x24), w3p[4], accv);
    accv = EWFMA(selu4(x25), w3p[5], accv);
    accv = EWFMA(selu4(x26), w3p[6], accv);
    accv = EWFMA(selu4(x27), w3p[7], accv);
    float acc = sb3 + hsum4(accv);
    float sp = fmaxf(acc, 0.f) + log1pf(__expf(-fabsf(acc)));
    float w = sp + 0.1f;
    w = fminf(fmaxf(w, 0.1f), 10.f);
    out[e] = w;
}

extern "C" void kernel_launch(void* const* d_in, const int* in_sizes, int n_in,
                              void* d_out, int out_size, void* d_ws, size_t ws_size,
                              hipStream_t stream) {
    const float* edge_attr = (const float*)d_in[0];
    const float* msg_W1   = (const float*)d_in[1];
    const float* msg_b1   = (const float*)d_in[2];
    const float* msg_W2   = (const float*)d_in[3];
    const float* msg_b2   = (const float*)d_in[4];
    const float* gru_Wih  = (const float*)d_in[5];
    const float* gru_Whh  = (const float*)d_in[6];
    const float* gru_bih  = (const float*)d_in[7];
    const float* gru_bhh  = (const float*)d_in[8];
    const float* ro_W1    = (const float*)d_in[9];
    const float* ro_b1    = (const float*)d_in[10];
    const float* ro_W2    = (const float*)d_in[11];
    const float* ro_b2    = (const float*)d_in[12];
    const float* ro_W3    = (const float*)d_in[13];
    const float* ro_b3    = (const float*)d_in[14];
    const int* edge_index = (const int*)d_in[15];
    const int* dst = edge_index + E_EDGES;   // row 1 of (2,E)

    float*  h_ws = (float*)d_ws;                                  // E*20 f32
    __half* B0b  = (__half*)(h_ws + (size_t)E_EDGES * NF);        // E*32 f16
    __half* B1b  = B0b + (size_t)E_EDGES * 32;                    // E*32 f16

    dim3 block(256);
    dim3 gridB(E_EDGES / 256);
    dim3 gridS(E_EDGES * 2 / 256);     // 4 lanes per 2-edge pair

    kernel_B0<<<gridB, block, 0, stream>>>(edge_attr, msg_W1, msg_b1, B0b);
    // step 0: edge_attr -> h_ws; read B0b, write B1b
    kernel_step<1><<<gridS, block, 0, stream>>>(edge_attr, h_ws, B0b, B1b, dst,
        msg_W1, msg_b1, msg_W2, msg_b2, gru_Wih, gru_Whh, gru_bih, gru_bhh);
    // step 1: in place; read B1b, write B0b
    kernel_step<1><<<gridS, block, 0, stream>>>(h_ws, h_ws, B1b, B0b, dst,
        msg_W1, msg_b1, msg_W2, msg_b2, gru_Wih, gru_Whh, gru_bih, gru_bhh);
    // step 2: read B0b, write B1b
    kernel_step<1><<<gridS, block, 0, stream>>>(h_ws, h_ws, B0b, B1b, dst,
        msg_W1, msg_b1, msg_W2, msg_b2, gru_Wih, gru_Whh, gru_bih, gru_bhh);
    // step 3: read B1b, no B write
    kernel_step<0><<<gridS, block, 0, stream>>>(h_ws, h_ws, B1b, B0b, dst,
        msg_W1, msg_b1, msg_W2, msg_b2, gru_Wih, gru_Whh, gru_bih, gru_bhh);

    kernel_readout<<<gridB, block, 0, stream>>>(h_ws, ro_W1, ro_b1, ro_W2, ro_b2,
                                                ro_W3, ro_b3, (float*)d_out);
}

// Round 11
// 562.563 us; speedup vs baseline: 1.0440x; 1.0440x over previous
//
#include <hip/hip_runtime.h>
#include <hip/hip_fp16.h>

#define E_EDGES 320000
#define NF 20

typedef float v4 __attribute__((ext_vector_type(4)));
typedef float v2f __attribute__((ext_vector_type(2)));

#if defined(__has_builtin)
# if __has_builtin(__builtin_elementwise_fma)
#  define EWFMA(a,b,c) __builtin_elementwise_fma((a),(b),(c))
# endif
#endif
#ifndef EWFMA
# define EWFMA(a,b,c) ((a)*(b)+(c))
#endif
#if defined(__has_builtin)
# if __has_builtin(__builtin_elementwise_max)
#  define EWMAX(a,b) __builtin_elementwise_max((a),(b))
#  define EWMIN(a,b) __builtin_elementwise_min((a),(b))
# endif
#endif

#define SELU_S 1.0507009873554805f
#define SELU_KA (1.0507009873554805f * 1.6732632423543772f)

__device__ __forceinline__ v4 bc4(float s) { return (v4){s, s, s, s}; }
__device__ __forceinline__ v4 v4z() { return (v4){0.f, 0.f, 0.f, 0.f}; }

__device__ __forceinline__ float selu_f(float x) {
    float p = fmaxf(x, 0.f);
    float m = fminf(x, 0.f);
    float e = __expf(m);
    return fmaf(SELU_S, p, SELU_KA * (e - 1.f));
}
__device__ __forceinline__ float sigmoid_f(float x) {
    return 1.f / (1.f + __expf(-x));
}
__device__ __forceinline__ v4 exp4(v4 m) {
    return (v4){__expf(m.x), __expf(m.y), __expf(m.z), __expf(m.w)};
}
__device__ __forceinline__ v4 selu4(v4 x) {
#ifdef EWMAX
    v4 p = EWMAX(x, v4z());
    v4 m = EWMIN(x, v4z());
#else
    v4 p = {fmaxf(x.x,0.f), fmaxf(x.y,0.f), fmaxf(x.z,0.f), fmaxf(x.w,0.f)};
    v4 m = {fminf(x.x,0.f), fminf(x.y,0.f), fminf(x.z,0.f), fminf(x.w,0.f)};
#endif
    return EWFMA(bc4(SELU_S), p, EWFMA(bc4(SELU_KA), exp4(m), bc4(-SELU_KA)));
}

__device__ __forceinline__ float hsum4(v4 x) {
    v2f lo = __builtin_shufflevector(x, x, 0, 1);
    v2f hi = __builtin_shufflevector(x, x, 2, 3);
    v2f h = lo + hi;
    return h.x + h.y;
}

__device__ __forceinline__ float dot20v(v4 a0, v4 a1, v4 a2, v4 a3, v4 a4,
                                        const v4* __restrict__ w) {
    v4 w0 = w[0], w1 = w[1], w2 = w[2], w3 = w[3], w4 = w[4];
    v4 x = a0 * w0;
    x = EWFMA(a1, w1, x); x = EWFMA(a2, w2, x);
    x = EWFMA(a3, w3, x); x = EWFMA(a4, w4, x);
    return hsum4(x);
}
__device__ __forceinline__ void dot20_dualv(const v4* __restrict__ w,
    v4 a0, v4 a1, v4 a2, v4 a3, v4 a4,
    v4 b0, v4 b1, v4 b2, v4 b3, v4 b4,
    float& r0, float& r1)
{
    v4 w0 = w[0], w1 = w[1], w2 = w[2], w3 = w[3], w4 = w[4];
    v4 xa = a0 * w0;
    xa = EWFMA(a1, w1, xa); xa = EWFMA(a2, w2, xa);
    xa = EWFMA(a3, w3, xa); xa = EWFMA(a4, w4, xa);
    v4 xb = b0 * w0;
    xb = EWFMA(b1, w1, xb); xb = EWFMA(b2, w2, xb);
    xb = EWFMA(b3, w3, xb); xb = EWFMA(b4, w4, xb);
    r0 = hsum4(xa);
    r1 = hsum4(xb);
}
__device__ __forceinline__ void h8_to_v4x2(uint4 r, v4& lo, v4& hi) {
    float2 fa = __half22float2(__builtin_bit_cast(__half2, r.x));
    float2 fb = __half22float2(__builtin_bit_cast(__half2, r.y));
    float2 fc = __half22float2(__builtin_bit_cast(__half2, r.z));
    float2 fd = __half22float2(__builtin_bit_cast(__half2, r.w));
    lo = (v4){fa.x, fa.y, fb.x, fb.y};
    hi = (v4){fc.x, fc.y, fd.x, fd.y};
}
__device__ __forceinline__ uint4 f8_to_h8(v4 lo, v4 hi) {
    uint4 r;
    r.x = __builtin_bit_cast(unsigned, __floats2half2_rn(lo.x, lo.y));
    r.y = __builtin_bit_cast(unsigned, __floats2half2_rn(lo.z, lo.w));
    r.z = __builtin_bit_cast(unsigned, __floats2half2_rn(hi.x, hi.y));
    r.w = __builtin_bit_cast(unsigned, __floats2half2_rn(hi.z, hi.w));
    return r;
}

#define FOR20(X) \
  X(0, v0.x) X(1, v0.y) X(2, v0.z) X(3, v0.w) \
  X(4, v1.x) X(5, v1.y) X(6, v1.z) X(7, v1.w) \
  X(8, v2.x) X(9, v2.y) X(10, v2.z) X(11, v2.w) \
  X(12, v3.x) X(13, v3.y) X(14, v3.z) X(15, v3.w) \
  X(16, v4v.x) X(17, v4v.y) X(18, v4v.z) X(19, v4v.w)

#define FOR20_2(X) \
  X(0, va0.x, vb0.x) X(1, va0.y, vb0.y) X(2, va0.z, vb0.z) X(3, va0.w, vb0.w) \
  X(4, va1.x, vb1.x) X(5, va1.y, vb1.y) X(6, va1.z, vb1.z) X(7, va1.w, vb1.w) \
  X(8, va2.x, vb2.x) X(9, va2.y, vb2.y) X(10, va2.z, vb2.z) X(11, va2.w, vb2.w) \
  X(12, va3.x, vb3.x) X(13, va3.y, vb3.y) X(14, va3.z, vb3.z) X(15, va3.w, vb3.w) \
  X(16, va4.x, vb4.x) X(17, va4.y, vb4.y) X(18, va4.z, vb4.z) X(19, va4.w, vb4.w)

#define FOR8S2(X) \
  X(0, sa0.x, sb0.x) X(1, sa0.y, sb0.y) X(2, sa0.z, sb0.z) X(3, sa0.w, sb0.w) \
  X(4, sa1.x, sb1.x) X(5, sa1.y, sb1.y) X(6, sa1.z, sb1.z) X(7, sa1.w, sb1.w)

// B[e][o] = sum_f h[e][f] * W1[20+f][o] + b1[o], fp16 output
__global__ void __launch_bounds__(256) kernel_B0(
    const float* __restrict__ h, const float* __restrict__ W1,
    const float* __restrict__ b1, __half* __restrict__ B)
{
    __shared__ __align__(16) float sw[640];
    __shared__ __align__(16) float sbias[32];
    for (int i = threadIdx.x; i < 640; i += 256) sw[i] = W1[640 + i];
    if (threadIdx.x < 32) sbias[threadIdx.x] = b1[threadIdx.x];
    __syncthreads();
    int e = blockIdx.x * 256 + threadIdx.x;
    const v4* hp = reinterpret_cast<const v4*>(h + (size_t)e * NF);
    v4 v0 = hp[0], v1 = hp[1], v2 = hp[2], v3 = hp[3], v4v = hp[4];
    const v4* bi = reinterpret_cast<const v4*>(sbias);
    v4 c0 = bi[0], c1 = bi[1], c2 = bi[2], c3 = bi[3],
       c4 = bi[4], c5 = bi[5], c6 = bi[6], c7 = bi[7];
    #define BSTEP(f, hf) { v4 t_ = bc4(hf); const v4* w_ = (const v4*)&sw[(f)*32]; \
        c0 = EWFMA(t_, w_[0], c0); c1 = EWFMA(t_, w_[1], c1); \
        c2 = EWFMA(t_, w_[2], c2); c3 = EWFMA(t_, w_[3], c3); \
        c4 = EWFMA(t_, w_[4], c4); c5 = EWFMA(t_, w_[5], c5); \
        c6 = EWFMA(t_, w_[6], c6); c7 = EWFMA(t_, w_[7], c7); }
    FOR20(BSTEP)
    #undef BSTEP
    uint4* Bp = reinterpret_cast<uint4*>(B + (size_t)e * 32);
    Bp[0] = f8_to_h8(c0, c1); Bp[1] = f8_to_h8(c2, c3);
    Bp[2] = f8_to_h8(c4, c5); Bp[3] = f8_to_h8(c6, c7);
}

// One step. 4 lanes/quad, 2 edges/thread, fp16 B gather, rolled GRU, pk-fp32.
// Gather uses split-selu accumulation: S_acc = scale*Σmax + ka*Σexp (same
// accumulator, two FMAs — 2 fewer slots/float4 than selu-then-add), with
// the constant −16ka applied once after the loop. VGPR must stay <=64
// (R10: 68 VGPR -> 7 waves/SIMD -> +17% dur. The cliff is real.)
__global__ void __launch_bounds__(256) kernel_step(
    const float* __restrict__ h_in, float* __restrict__ h_out,
    const __half* __restrict__ Br, const int* __restrict__ dst,
    const float* __restrict__ W1, const float* __restrict__ W2, const float* __restrict__ b2,
    const float* __restrict__ Wih, const float* __restrict__ Whh,
    const float* __restrict__ bih, const float* __restrict__ bhh)
{
    __shared__ __align__(16) float sW1[640];   // rows 0-19 of msg_W1 (20,32)
    __shared__ __align__(16) float sW2[640];   // (32,20)
    __shared__ __align__(16) float sb2v[20];
    __shared__ __align__(16) float sWih[1200]; // (60,20)
    __shared__ __align__(16) float sWhh[1200];
    __shared__ float sbih[60];
    __shared__ float sbhh[60];
    for (int i = threadIdx.x; i < 640; i += 256) { sW1[i] = W1[i]; sW2[i] = W2[i]; }
    for (int i = threadIdx.x; i < 1200; i += 256) { sWih[i] = Wih[i]; sWhh[i] = Whh[i]; }
    if (threadIdx.x < 20) sb2v[threadIdx.x] = b2[threadIdx.x];
    else if (threadIdx.x >= 64 && threadIdx.x < 124) sbih[threadIdx.x - 64] = bih[threadIdx.x - 64];
    else if (threadIdx.x >= 128 && threadIdx.x < 188) sbhh[threadIdx.x - 128] = bhh[threadIdx.x - 128];
    __syncthreads();

    int t = blockIdx.x * 256 + threadIdx.x;
    int p = t >> 2;
    int q = t & 3;
    int ob = q * 8;
    int e0 = p * 2, e1 = p * 2 + 1;

    int2 dd = *reinterpret_cast<const int2*>(dst + e0);
    int d0 = dd.x, d1 = dd.y;

    const v4* hp0 = reinterpret_cast<const v4*>(h_in + (size_t)e0 * NF);
    const v4* hp1 = reinterpret_cast<const v4*>(h_in + (size_t)e1 * NF);
    v4 va0 = hp0[0], va1 = hp0[1], va2 = hp0[2], va3 = hp0[3], va4 = hp0[4];
    v4 vb0 = hp1[0], vb1 = hp1[1], vb2 = hp1[2], vb3 = hp1[3], vb4 = hp1[4];

    // A slices for both edges (shared LDS weight reads, pk-fma)
    v4 aa0 = v4z(), aa1 = v4z(), ab0 = v4z(), ab1 = v4z();
    #define ASTEP2(f, h0, h1) { const v4* w_ = (const v4*)&sW1[(f)*32 + ob]; \
        v4 w0_ = w_[0], w1_ = w_[1]; \
        v4 t0_ = bc4(h0), t1_ = bc4(h1); \
        aa0 = EWFMA(t0_, w0_, aa0); aa1 = EWFMA(t0_, w1_, aa1); \
        ab0 = EWFMA(t1_, w0_, ab0); ab1 = EWFMA(t1_, w1_, ab1); }
    FOR20_2(ASTEP2)
    #undef ASTEP2

    // gather 16 fp16 rows per edge; split-selu accumulate (no extra regs)
    const uint4* Bp0 = reinterpret_cast<const uint4*>(Br) + (size_t)d0 * 64 + q;
    const uint4* Bp1 = reinterpret_cast<const uint4*>(Br) + (size_t)d1 * 64 + q;
    v4 sa0 = v4z(), sa1 = v4z(), sb0 = v4z(), sb1 = v4z();
    {
        const v4 ks = bc4(SELU_S);
        const v4 ka = bc4(SELU_KA);
        const v4 z = v4z();
        #pragma unroll 4
        for (int k = 0; k < 16; k++) {
            uint4 rA = Bp0[k * 4];
            uint4 rB = Bp1[k * 4];
            v4 loA, hiA, loB, hiB;
            h8_to_v4x2(rA, loA, hiA);
            h8_to_v4x2(rB, loB, hiB);
            #define ACC1(S_, t_) { v4 tt_ = (t_); \
                v4 p_ = EWMAX(tt_, z); v4 m_ = EWMIN(tt_, z); \
                S_ = EWFMA(ks, p_, S_); S_ = EWFMA(ka, exp4(m_), S_); }
            ACC1(sa0, aa0 + loA)
            ACC1(sa1, aa1 + hiA)
            ACC1(sb0, ab0 + loB)
            ACC1(sb1, ab1 + hiB)
            #undef ACC1
        }
        v4 cc = bc4(-16.f * SELU_KA);
        sa0 = sa0 + cc; sa1 = sa1 + cc;
        sb0 = sb0 + cc; sb1 = sb1 + cc;
    }

    // partial agg (shared W2 rows, pk-fma)
    v4 ga0 = v4z(), ga1 = v4z(), ga2 = v4z(), ga3 = v4z(), ga4 = v4z();
    v4 gb0 = v4z(), gb1 = v4z(), gb2 = v4z(), gb3 = v4z(), gb4 = v4z();
    #define AGGS2(j, c0_, c1_) { const v4* w_ = (const v4*)&sW2[(ob + (j)) * 20]; \
        v4 w0_ = w_[0], w1_ = w_[1], w2_ = w_[2], w3_ = w_[3], w4_ = w_[4]; \
        v4 u_ = bc4(c0_), vv_ = bc4(c1_); \
        ga0 = EWFMA(u_, w0_, ga0); ga1 = EWFMA(u_, w1_, ga1); ga2 = EWFMA(u_, w2_, ga2); \
        ga3 = EWFMA(u_, w3_, ga3); ga4 = EWFMA(u_, w4_, ga4); \
        gb0 = EWFMA(vv_, w0_, gb0); gb1 = EWFMA(vv_, w1_, gb1); gb2 = EWFMA(vv_, w2_, gb2); \
        gb3 = EWFMA(vv_, w3_, gb3); gb4 = EWFMA(vv_, w4_, gb4); }
    FOR8S2(AGGS2)
    #undef AGGS2

    // quad butterfly
    #define BF1(r_, m_) { v4 t_ = { __shfl_xor(r_.x, m_), __shfl_xor(r_.y, m_), \
                                    __shfl_xor(r_.z, m_), __shfl_xor(r_.w, m_) }; \
                          r_ = r_ + t_; }
    #define BFLY(m_) BF1(ga0, m_) BF1(ga1, m_) BF1(ga2, m_) BF1(ga3, m_) BF1(ga4, m_) \
                     BF1(gb0, m_) BF1(gb1, m_) BF1(gb2, m_) BF1(gb3, m_) BF1(gb4, m_)
    BFLY(1)
    BFLY(2)
    #undef BFLY
    #undef BF1

    {
        const v4* b2p = reinterpret_cast<const v4*>(sb2v);
        v4 sixteen = bc4(16.f);
        v4 c0 = b2p[0], c1 = b2p[1], c2 = b2p[2], c3 = b2p[3], c4 = b2p[4];
        ga0 = EWFMA(sixteen, c0, ga0); ga1 = EWFMA(sixteen, c1, ga1); ga2 = EWFMA(sixteen, c2, ga2);
        ga3 = EWFMA(sixteen, c3, ga3); ga4 = EWFMA(sixteen, c4, ga4);
        gb0 = EWFMA(sixteen, c0, gb0); gb1 = EWFMA(sixteen, c1, gb1); gb2 = EWFMA(sixteen, c2, gb2);
        gb3 = EWFMA(sixteen, c3, gb3); gb4 = EWFMA(sixteen, c4, gb4);
    }

    // GRU: 5 channels per lane, ROLLED (dynamic index -> LDS only; VGPR=64)
    for (int i = 0; i < 5; i++) {
        int c = q * 5 + i;
        float ir0, ir1, iz0, iz1, in0, in1, hr0, hr1, hz0, hz1, hn0, hn1;
        dot20_dualv((const v4*)&sWih[c * 20],        ga0, ga1, ga2, ga3, ga4,
                    gb0, gb1, gb2, gb3, gb4, ir0, ir1);
        dot20_dualv((const v4*)&sWih[(20 + c) * 20], ga0, ga1, ga2, ga3, ga4,
                    gb0, gb1, gb2, gb3, gb4, iz0, iz1);
        dot20_dualv((const v4*)&sWih[(40 + c) * 20], ga0, ga1, ga2, ga3, ga4,
                    gb0, gb1, gb2, gb3, gb4, in0, in1);
        dot20_dualv((const v4*)&sWhh[c * 20],        va0, va1, va2, va3, va4,
                    vb0, vb1, vb2, vb3, vb4, hr0, hr1);
        dot20_dualv((const v4*)&sWhh[(20 + c) * 20], va0, va1, va2, va3, va4,
                    vb0, vb1, vb2, vb3, vb4, hz0, hz1);
        dot20_dualv((const v4*)&sWhh[(40 + c) * 20], va0, va1, va2, va3, va4,
                    vb0, vb1, vb2, vb3, vb4, hn0, hn1);
        float bi_r = sbih[c], bi_z = sbih[20 + c], bi_n = sbih[40 + c];
        float bh_r = sbhh[c], bh_z = sbhh[20 + c], bh_n = sbhh[40 + c];
        {
            float r = sigmoid_f(bi_r + ir0 + bh_r + hr0);
            float z = sigmoid_f(bi_z + iz0 + bh_z + hz0);
            float xn = bi_n + in0 + r * (bh_n + hn0);
            xn = fminf(fmaxf(xn, -20.f), 20.f);
            float tt = __expf(2.f * xn);
            float n = (tt - 1.f) / (tt + 1.f);
            float hc = h_in[(size_t)e0 * NF + c];
            h_out[(size_t)e0 * NF + c] = (1.f - z) * n + z * hc;
        }
        {
            float r = sigmoid_f(bi_r + ir1 + bh_r + hr1);
            float z = sigmoid_f(bi_z + iz1 + bh_z + hz1);
            float xn = bi_n + in1 + r * (bh_n + hn1);
            xn = fminf(fmaxf(xn, -20.f), 20.f);
            float tt = __expf(2.f * xn);
            float n = (tt - 1.f) / (tt + 1.f);
            float hc = h_in[(size_t)e1 * NF + c];
            h_out[(size_t)e1 * NF + c] = (1.f - z) * n + z * hc;
        }
    }
}

__global__ void __launch_bounds__(256) kernel_readout(
    const float* __restrict__ h,
    const float* __restrict__ W1, const float* __restrict__ b1,
    const float* __restrict__ W2, const float* __restrict__ b2,
    const float* __restrict__ W3, const float* __restrict__ b3,
    float* __restrict__ out)
{
    __shared__ __align__(16) float sW1t[1280]; // transposed: (64,20)
    __shared__ float sb1[64];
    __shared__ __align__(16) float sW2[2048];  // (64,32)
    __shared__ __align__(16) float sb2v[32];
    __shared__ __align__(16) float sW3[32];
    __shared__ float sb3;
    for (int i = threadIdx.x; i < 1280; i += 256) {
        int f = i >> 6, o = i & 63;
        sW1t[o * 20 + f] = W1[i];
    }
    for (int i = threadIdx.x; i < 2048; i += 256) sW2[i] = W2[i];
    if (threadIdx.x < 64) sb1[threadIdx.x] = b1[threadIdx.x];
    else if (threadIdx.x >= 64 && threadIdx.x < 96) sb2v[threadIdx.x - 64] = b2[threadIdx.x - 64];
    else if (threadIdx.x >= 96 && threadIdx.x < 128) sW3[threadIdx.x - 96] = W3[threadIdx.x - 96];
    if (threadIdx.x == 128) sb3 = b3[0];
    __syncthreads();

    int e = blockIdx.x * 256 + threadIdx.x;
    const v4* hp = reinterpret_cast<const v4*>(h + (size_t)e * NF);
    v4 v0 = hp[0], v1 = hp[1], v2 = hp[2], v3 = hp[3], v4v = hp[4];

    const v4* b2p = reinterpret_cast<const v4*>(sb2v);
    v4 x20 = b2p[0], x21 = b2p[1], x22 = b2p[2], x23 = b2p[3],
       x24 = b2p[4], x25 = b2p[5], x26 = b2p[6], x27 = b2p[7];
    for (int o = 0; o < 64; o++) {
        float x1 = sb1[o] + dot20v(v0, v1, v2, v3, v4v, (const v4*)&sW1t[o * 20]);
        x1 = selu_f(x1);
        v4 xb = bc4(x1);
        const v4* w = (const v4*)&sW2[o * 32];
        x20 = EWFMA(xb, w[0], x20); x21 = EWFMA(xb, w[1], x21);
        x22 = EWFMA(xb, w[2], x22); x23 = EWFMA(xb, w[3], x23);
        x24 = EWFMA(xb, w[4], x24); x25 = EWFMA(xb, w[5], x25);
        x26 = EWFMA(xb, w[6], x26); x27 = EWFMA(xb, w[7], x27);
    }
    const v4* w3p = reinterpret_cast<const v4*>(sW3);
    v4 accv = selu4(x20) * w3p[0];
    accv = EWFMA(selu4(x21), w3p[1], accv);
    accv = EWFMA(selu4(x22), w3p[2], accv);
    accv = EWFMA(selu4(x23), w3p[3], accv);
    accv = EWFMA(selu4(x24), w3p[4], accv);
    accv = EWFMA(selu4(x25), w3p[5], accv);
    accv = EWFMA(selu4(x26), w3p[6], accv);
    accv = EWFMA(selu4(x27), w3p[7], accv);
    float acc = sb3 + hsum4(accv);
    float sp = fmaxf(acc, 0.f) + log1pf(__expf(-fabsf(acc)));
    float w = sp + 0.1f;
    w = fminf(fmaxf(w, 0.1f), 10.f);
    out[e] = w;
}

extern "C" void kernel_launch(void* const* d_in, const int* in_sizes, int n_in,
                              void* d_out, int out_size, void* d_ws, size_t ws_size,
                              hipStream_t stream) {
    const float* edge_attr = (const float*)d_in[0];
    const float* msg_W1   = (const float*)d_in[1];
    const float* msg_b1   = (const float*)d_in[2];
    const float* msg_W2   = (const float*)d_in[3];
    const float* msg_b2   = (const float*)d_in[4];
    const float* gru_Wih  = (const float*)d_in[5];
    const float* gru_Whh  = (const float*)d_in[6];
    const float* gru_bih  = (const float*)d_in[7];
    const float* gru_bhh  = (const float*)d_in[8];
    const float* ro_W1    = (const float*)d_in[9];
    const float* ro_b1    = (const float*)d_in[10];
    const float* ro_W2    = (const float*)d_in[11];
    const float* ro_b2    = (const float*)d_in[12];
    const float* ro_W3    = (const float*)d_in[13];
    const float* ro_b3    = (const float*)d_in[14];
    const int* edge_index = (const int*)d_in[15];
    const int* dst = edge_index + E_EDGES;   // row 1 of (2,E)

    float*  h_ws = (float*)d_ws;                                  // E*20 f32
    __half* Bt   = (__half*)(h_ws + (size_t)E_EDGES * NF);        // E*32 f16

    dim3 block(256);
    dim3 gridB(E_EDGES / 256);
    dim3 gridS(E_EDGES * 2 / 256);     // 4 lanes per 2-edge pair

    const float* hin = edge_attr;
    for (int s = 0; s < 4; s++) {
        kernel_B0<<<gridB, block, 0, stream>>>(hin, msg_W1, msg_b1, Bt);
        kernel_step<<<gridS, block, 0, stream>>>(hin, h_ws, Bt, dst,
            msg_W1, msg_W2, msg_b2, gru_Wih, gru_Whh, gru_bih, gru_bhh);
        hin = h_ws;
    }
    kernel_readout<<<gridB, block, 0, stream>>>(h_ws, ro_W1, ro_b1, ro_W2, ro_b2,
                                                ro_W3, ro_b3, (float*)d_out);
}